// Round 7
// baseline (351.552 us; speedup 1.0000x reference)
//
#include <hip/hip_runtime.h>
#include <hip/hip_bf16.h>

// GCN 2-layer: out = A' relu(A' (xW1) + b1) W2 + b2, A' = D^-1/2 (A+I) D^-1/2
// R7: GEMM K-loop software-pipelined: LDS double-buffer, B prefetch via
// global_load_lds issued right after barrier (overlaps MFMA), A prefetched
// into registers during MFMA, ONE barrier per iteration.
// Hs bf16 messages; CSR two-level binning; bf16x3 fp32-accurate GEMMs.
// Assumes N <= 65535 (harness: N=50000) so (d,s) packs into 32 bits.

typedef __attribute__((ext_vector_type(8))) short short8;
typedef __attribute__((ext_vector_type(4))) float f32x4;

#define BSHIFT 9
#define BSIZE 512
constexpr int NBMAX = 128;
constexpr int CAP = 32768;   // pair slots per coarse bucket (mean ~16.3K)
constexpr int CHUNK = 4096;  // edges per binA block

__device__ __forceinline__ unsigned short bf16_bits(float f) {
  __hip_bfloat16 h = __float2bfloat16(f);
  return *(unsigned short*)&h;
}
__device__ __forceinline__ float bf16_f(unsigned short u) {
  __hip_bfloat16 h = *(__hip_bfloat16*)&u;
  return __bfloat162float(h);
}

__device__ __forceinline__ void gload_lds16(const void* g, void* l) {
  __builtin_amdgcn_global_load_lds(
      (const __attribute__((address_space(1))) unsigned*)g,
      (__attribute__((address_space(3))) unsigned*)l, 16, 0, 0);
}

__device__ __forceinline__ int edge_at(const void* p, long long i, int is64) {
  return is64 ? (int)((const long long*)p)[i] : ((const int*)p)[i];
}

// Detect int64 edge storage (odd 32-bit words all zero over sample); init ccur.
__global__ void k_detect(const int* __restrict__ w, int* flag, int nwords,
                         int* __restrict__ ccur, int NB) {
  __shared__ int nz;
  if (threadIdx.x == 0) nz = 0;
  __syncthreads();
  for (int i = 1 + 2 * (int)threadIdx.x; i < nwords; i += 2 * (int)blockDim.x)
    if (w[i] != 0) nz = 1;
  if ((int)threadIdx.x < NB) ccur[threadIdx.x] = (int)threadIdx.x * CAP;
  __syncthreads();
  if (threadIdx.x == 0) *flag = (nz == 0) ? 1 : 0;
}

// Coarse binning: LDS counting-sort of a 4096-edge chunk by bucket = d>>9,
// flush contiguous runs into fixed-capacity per-bucket pair regions.
__global__ __launch_bounds__(256) void k_binA(
    const void* __restrict__ eidx, const int* __restrict__ flag,
    int* __restrict__ ccur, unsigned* __restrict__ pairs, int E, int NB) {
  __shared__ int cnt[NBMAX];
  __shared__ int scn[NBMAX + 1];
  __shared__ int cur[NBMAX];
  __shared__ int gbase[NBMAX];
  __shared__ unsigned out[CHUNK];
  const int is64 = *flag;
  const int tid = threadIdx.x;
  const int cs = blockIdx.x * CHUNK;
  const int n = min(CHUNK, E - cs);
  for (int b = tid; b < NB; b += 256) cnt[b] = 0;
  __syncthreads();
  unsigned pk[CHUNK / 256];
#pragma unroll
  for (int it = 0; it < CHUNK / 256; ++it) {
    int i = cs + it * 256 + tid;
    unsigned p = 0xFFFFFFFFu;
    if (i < E) {
      int s = edge_at(eidx, i, is64);
      int d = edge_at(eidx, (long long)E + i, is64);
      p = ((unsigned)d << 16) | (unsigned)s;
      atomicAdd(&cnt[d >> BSHIFT], 1);
    }
    pk[it] = p;
  }
  __syncthreads();
  if (tid < NB) scn[tid + 1] = cnt[tid];
  if (tid == 0) scn[0] = 0;
  __syncthreads();
  for (int off = 1; off < NB; off <<= 1) {
    int t = 0;
    if (tid < NB && tid + 1 > off) t = scn[tid + 1 - off];
    __syncthreads();
    if (tid < NB && tid + 1 > off) scn[tid + 1] += t;
    __syncthreads();
  }
  if (tid < NB) {
    cur[tid] = scn[tid];
    gbase[tid] = (cnt[tid] > 0) ? atomicAdd(&ccur[tid], cnt[tid]) : 0;
  }
  __syncthreads();
#pragma unroll
  for (int it = 0; it < CHUNK / 256; ++it) {
    unsigned p = pk[it];
    if (p != 0xFFFFFFFFu) {
      int b = (int)(p >> (16 + BSHIFT));
      int pos = atomicAdd(&cur[b], 1);
      out[pos] = p;
    }
  }
  __syncthreads();
  for (int p2 = tid; p2 < n; p2 += 256) {
    unsigned v = out[p2];
    int b = (int)(v >> (16 + BSHIFT));
    pairs[gbase[b] + (p2 - scn[b])] = v;  // contiguous run per bucket
  }
}

// Scan bucket totals -> bbase (elist/rowptr base per bucket); rowptr[N] = E.
__global__ __launch_bounds__(128) void k_scanb(
    const int* __restrict__ ccur, int* __restrict__ bbase,
    int* __restrict__ rowptr, int NB, int N, int E) {
  __shared__ int buf[NBMAX];
  int tid = threadIdx.x;
  int v = (tid < NB) ? (ccur[tid] - tid * CAP) : 0;
  buf[tid] = v;
  __syncthreads();
  for (int off = 1; off < NBMAX; off <<= 1) {
    int t = (tid >= off) ? buf[tid - off] : 0;
    __syncthreads();
    buf[tid] += t;
    __syncthreads();
  }
  if (tid < NB) bbase[tid] = buf[tid] - v;
  if (tid == 0) rowptr[N] = E;
}

// Per-bucket: LDS histogram + scan -> rowptr/dinv; place s into dense
// elist window via LDS cursors (no global atomics).
__global__ __launch_bounds__(256) void k_binB(
    const unsigned* __restrict__ pairs, const int* __restrict__ ccur,
    const int* __restrict__ bbase, int* __restrict__ rowptr,
    float* __restrict__ dinv, int* __restrict__ elist, int N) {
  __shared__ int hist[BSIZE];
  __shared__ int loc[BSIZE];
  const int b = blockIdx.x;
  const int tid = threadIdx.x;
  const int nbeg = b * CAP;
  const int cntb = ccur[b] - nbeg;
  const int base = bbase[b];
  const int j0 = tid, j1 = tid + 256;
  hist[j0] = 0; hist[j1] = 0;
  __syncthreads();
  for (int i = tid; i < cntb; i += 256) {
    unsigned v = pairs[nbeg + i];
    atomicAdd(&hist[(v >> 16) & (BSIZE - 1)], 1);
  }
  __syncthreads();
  loc[j0] = hist[j0]; loc[j1] = hist[j1];
  __syncthreads();
  for (int off = 1; off < BSIZE; off <<= 1) {
    int v0 = (j0 >= off) ? loc[j0 - off] : 0;
    int v1 = (j1 >= off) ? loc[j1 - off] : 0;
    __syncthreads();
    loc[j0] += v0; loc[j1] += v1;
    __syncthreads();
  }
  int c0 = base + loc[j0] - hist[j0];
  int c1 = base + loc[j1] - hist[j1];
  int gd0 = b * BSIZE + j0, gd1 = b * BSIZE + j1;
  if (gd0 < N) { rowptr[gd0] = c0; dinv[gd0] = rsqrtf((float)(hist[j0] + 1)); }
  if (gd1 < N) { rowptr[gd1] = c1; dinv[gd1] = rsqrtf((float)(hist[j1] + 1)); }
  __syncthreads();
  hist[j0] = c0; hist[j1] = c1;  // reuse as cursors
  __syncthreads();
  for (int i = tid; i < cntb; i += 256) {
    unsigned v = pairs[nbeg + i];
    int p = atomicAdd(&hist[(v >> 16) & (BSIZE - 1)], 1);
    elist[p] = (int)(v & 0xFFFFu);
  }
}

// Both weights: W[K,N] fp32 -> Whi/Wlo[N,K] bf16 (transposed), hi/lo split.
__global__ void k_prepw2(const float* __restrict__ W1, unsigned short* __restrict__ W1h,
                         unsigned short* __restrict__ W1l,
                         const float* __restrict__ W2, unsigned short* __restrict__ W2h,
                         unsigned short* __restrict__ W2l) {
  int o = blockIdx.x * blockDim.x + threadIdx.x;
  const float* W; unsigned short *Wh, *Wl; int K, N;
  if (o < 512 * 128) { W = W1; Wh = W1h; Wl = W1l; K = 512; N = 128; }
  else { o -= 512 * 128; if (o >= 128 * 64) return; W = W2; Wh = W2h; Wl = W2l; K = 128; N = 64; }
  int n = o / K, k = o % K;
  float w = W[(long long)k * N + n];
  unsigned short hb = bf16_bits(w);
  unsigned short lb = bf16_bits(w - bf16_f(hb));
  Wh[o] = hb;
  Wl[o] = lb;
}

// Pipelined MFMA GEMM: Hs(bf16) = (X[M,K] @ W[K,NOUT]) * dinv[row], bf16x3.
// Wave tile WM x 64; wave grid WY x WX (WY*WX = 4); BM = WM*WY, BN = 64*WX.
// LDS rows KC=32 bf16 = 64 B unpadded (global_load_lds order matches exactly).
// K-loop: LDS double-buffer; B prefetch (async->LDS) + A prefetch (->regs)
// overlap MFMA; one barrier per iteration.
template <int K, int NOUT, int WM, int WY, int WX>
__global__ __launch_bounds__(256) void k_gemm_mfma(
    const float* __restrict__ X, const unsigned short* __restrict__ Whi,
    const unsigned short* __restrict__ Wlo, const float* __restrict__ dinv,
    unsigned short* __restrict__ Hs, int M) {
  constexpr int BM = WM * WY;
  constexpr int BN = 64 * WX;
  constexpr int KC = 32;
  constexpr int I = WM / 16;
  constexpr int AIT = BM / 32;          // float4 A-loads per thread per tile
  constexpr int BIT = (BN * 4) / 256;   // 16B B-chunks per thread per tile
  static_assert(WY * WX == 4, "4 waves");
  static_assert(BN == NOUT, "block covers full N");
  __shared__ unsigned short Ah[2][BM][KC], Al[2][BM][KC];
  __shared__ unsigned short Bh[2][BN][KC], Bl[2][BN][KC];
  const int tid = threadIdx.x;
  const int lane = tid & 63, wv = tid >> 6;
  const int wy = wv / WX, wx = wv % WX;
  const int fm = lane & 15;
  const int fq = lane >> 4;
  const int base = blockIdx.x * BM;

  float4 av[AIT];

  auto loadA = [&](int k0) {
#pragma unroll
    for (int it = 0; it < AIT; ++it) {
      int chunk = tid + it * 256;
      int r = chunk >> 3, c = chunk & 7;
      av[it] = make_float4(0.f, 0.f, 0.f, 0.f);
      if (base + r < M)
        av[it] = *(const float4*)&X[(long long)(base + r) * K + k0 + c * 4];
    }
  };
  auto writeA = [&](int buf) {
#pragma unroll
    for (int it = 0; it < AIT; ++it) {
      int chunk = tid + it * 256;
      int r = chunk >> 3, c = chunk & 7;
      float4 v = av[it];
      ushort4 hv, lv;
      hv.x = bf16_bits(v.x); lv.x = bf16_bits(v.x - bf16_f(hv.x));
      hv.y = bf16_bits(v.y); lv.y = bf16_bits(v.y - bf16_f(hv.y));
      hv.z = bf16_bits(v.z); lv.z = bf16_bits(v.z - bf16_f(hv.z));
      hv.w = bf16_bits(v.w); lv.w = bf16_bits(v.w - bf16_f(hv.w));
      *(ushort4*)&Ah[buf][r][c * 4] = hv;
      *(ushort4*)&Al[buf][r][c * 4] = lv;
    }
  };
  auto loadB = [&](int buf, int k0) {
#pragma unroll
    for (int it = 0; it < BIT; ++it) {
      int cb = it * 256 + wv * 64;  // wave-uniform chunk base
      int chunk = cb + lane;
      int n = chunk >> 2, cc = chunk & 3;
      const long long go = (long long)n * K + k0 + cc * 8;
      gload_lds16(&Whi[go], (unsigned short*)Bh[buf] + (size_t)cb * 8);
      gload_lds16(&Wlo[go], (unsigned short*)Bl[buf] + (size_t)cb * 8);
    }
  };

  f32x4 acc[I][4];
#pragma unroll
  for (int i = 0; i < I; ++i)
#pragma unroll
    for (int j = 0; j < 4; ++j) acc[i][j] = (f32x4){0.f, 0.f, 0.f, 0.f};

  // prologue: stage tile 0 into buffer 0
  loadA(0);
  loadB(0, 0);
  writeA(0);
  __syncthreads();

  constexpr int NIT = K / KC;
  for (int kk = 0; kk < NIT; ++kk) {
    const int buf = kk & 1;
    const int nxt = buf ^ 1;
    const bool more = (kk + 1) < NIT;
    // prefetch tile kk+1: B async into other LDS buffer (overlaps MFMA)
    if (more) loadB(nxt, (kk + 1) * KC);
    // fragments for tile kk
    short8 ah[I], al[I], bh[4], bl[4];
#pragma unroll
    for (int i = 0; i < I; ++i) {
      ah[i] = *(short8*)&Ah[buf][wy * WM + i * 16 + fm][fq * 8];
      al[i] = *(short8*)&Al[buf][wy * WM + i * 16 + fm][fq * 8];
    }
#pragma unroll
    for (int j = 0; j < 4; ++j) {
      bh[j] = *(short8*)&Bh[buf][wx * 64 + j * 16 + fm][fq * 8];
      bl[j] = *(short8*)&Bl[buf][wx * 64 + j * 16 + fm][fq * 8];
    }
    // prefetch A tile kk+1 into registers (overlaps MFMA)
    if (more) loadA((kk + 1) * KC);
    // MFMA tile kk
#pragma unroll
    for (int i = 0; i < I; ++i)
#pragma unroll
      for (int j = 0; j < 4; ++j) {
        acc[i][j] = __builtin_amdgcn_mfma_f32_16x16x32_bf16(ah[i], bh[j], acc[i][j], 0, 0, 0);
        acc[i][j] = __builtin_amdgcn_mfma_f32_16x16x32_bf16(ah[i], bl[j], acc[i][j], 0, 0, 0);
        acc[i][j] = __builtin_amdgcn_mfma_f32_16x16x32_bf16(al[i], bh[j], acc[i][j], 0, 0, 0);
      }
    if (more) {
      writeA(nxt);      // cvt + ds_write A tile kk+1
      __syncthreads();  // drains B gload_lds + A ds_writes for tile kk+1
    }
  }
  // epilogue: C/D layout col=lane&15, row=fq*4+reg
#pragma unroll
  for (int i = 0; i < I; ++i) {
#pragma unroll
    for (int reg = 0; reg < 4; ++reg) {
      int row = base + wy * WM + i * 16 + fq * 4 + reg;
      if (row < M) {
        float dv = dinv[row];
#pragma unroll
        for (int j = 0; j < 4; ++j)
          Hs[(long long)row * NOUT + wx * 64 + j * 16 + fm] =
              bf16_bits(acc[i][j][reg] * dv);
      }
    }
  }
}

// Accumulate 8 bf16 (one uint4) into 8 fp32.
__device__ __forceinline__ void acc8(float* a, uint4 u) {
  const unsigned* p = (const unsigned*)&u;
#pragma unroll
  for (int q = 0; q < 4; ++q) {
    unsigned w = p[q];
    a[2 * q]     += __uint_as_float(w << 16);
    a[2 * q + 1] += __uint_as_float(w & 0xFFFF0000u);
  }
}

// Gather-aggregate from bf16 Hs:
// OUT[d] = act(dinv[d] * (sum_{s in in(d)} Hs[s] + Hs[d]) + bias), fp32 out.
template <int C, bool RELU>
__global__ __launch_bounds__(256) void k_gather(
    const int* __restrict__ rowptr, const int* __restrict__ elist,
    const float* __restrict__ dinv, const unsigned short* __restrict__ Hs,
    const float* __restrict__ bias, float* __restrict__ OUT, int N) {
  constexpr int TPN = C / 8;      // threads per node (8 bf16 = 16 B each)
  constexpr int NPB = 256 / TPN;  // nodes per block
  const int node = blockIdx.x * NPB + (int)threadIdx.x / TPN;
  const int lane = (int)threadIdx.x % TPN;
  if (node >= N) return;
  const int col = lane * 8;
  const int beg = rowptr[node];
  const int end = rowptr[node + 1];
  float a0[8] = {0, 0, 0, 0, 0, 0, 0, 0};
  float a1[8] = {0, 0, 0, 0, 0, 0, 0, 0};
  acc8(a0, *(const uint4*)&Hs[(long long)node * C + col]);  // self-loop
  int e = beg;
  for (; e + 3 < end; e += 4) {
    int s0 = elist[e], s1 = elist[e + 1], s2 = elist[e + 2], s3 = elist[e + 3];
    uint4 v0 = *(const uint4*)&Hs[(long long)s0 * C + col];
    uint4 v1 = *(const uint4*)&Hs[(long long)s1 * C + col];
    uint4 v2 = *(const uint4*)&Hs[(long long)s2 * C + col];
    uint4 v3 = *(const uint4*)&Hs[(long long)s3 * C + col];
    acc8(a0, v0); acc8(a1, v1); acc8(a0, v2); acc8(a1, v3);
  }
  for (; e < end; ++e) {
    uint4 v0 = *(const uint4*)&Hs[(long long)elist[e] * C + col];
    acc8(a0, v0);
  }
  const float dv = dinv[node];
  float o[8];
#pragma unroll
  for (int i = 0; i < 8; ++i) {
    o[i] = (a0[i] + a1[i]) * dv + bias[col + i];
    if (RELU) o[i] = fmaxf(o[i], 0.f);
  }
  *(float4*)&OUT[(long long)node * C + col] = make_float4(o[0], o[1], o[2], o[3]);
  *(float4*)&OUT[(long long)node * C + col + 4] = make_float4(o[4], o[5], o[6], o[7]);
}

extern "C" void kernel_launch(void* const* d_in, const int* in_sizes, int n_in,
                              void* d_out, int out_size, void* d_ws, size_t ws_size,
                              hipStream_t stream) {
  const float* x  = (const float*)d_in[0];
  const void*  ei = d_in[1];
  const float* W1 = (const float*)d_in[2];
  const float* b1 = (const float*)d_in[3];
  const float* W2 = (const float*)d_in[4];
  const float* b2 = (const float*)d_in[5];
  float* out = (float*)d_out;
  const int N = in_sizes[0] / 512;  // 50000
  const int E = in_sizes[1] / 2;    // 1600000
  const int NB = (N + BSIZE - 1) >> BSHIFT;  // 98

  char* ws = (char*)d_ws;
  size_t off = 0;
  auto take = [&](size_t bytes) {
    void* p = ws + off;
    off = (off + bytes + 255) & ~(size_t)255;
    return p;
  };
  float* dinv   = (float*)take((size_t)N * 4);
  int*   flag   = (int*)take(4);
  int*   rowptr = (int*)take((size_t)(N + 1) * 4);
  int*   ccur   = (int*)take((size_t)NBMAX * 4);
  int*   bbase  = (int*)take((size_t)NBMAX * 4);
  int*   elist  = (int*)take((size_t)E * 4);
  unsigned short* Wt1h = (unsigned short*)take((size_t)512 * 128 * 2);
  unsigned short* Wt1l = (unsigned short*)take((size_t)512 * 128 * 2);
  unsigned short* Wt2h = (unsigned short*)take((size_t)128 * 64 * 2);
  unsigned short* Wt2l = (unsigned short*)take((size_t)128 * 64 * 2);
  unsigned short* Hs = (unsigned short*)take((size_t)N * 128 * 2);  // bf16
  float* h2     = (float*)take((size_t)N * 128 * 4);
  unsigned short* Hs2 = Hs;           // alias: Hs dead after k_gather<128>
  unsigned* pairs = (unsigned*)h2;    // alias: pairs dead before h2 written
                                      // (needs NB*CAP*4 = 12.8 MB <= 25.6 MB)

  const int B = 256;
  // CSR build (two-level binning, no global scatter atomics)
  k_detect<<<1, B, 0, stream>>>((const int*)ei, flag, 2048, ccur, NB);
  k_binA<<<(E + CHUNK - 1) / CHUNK, B, 0, stream>>>(ei, flag, ccur, pairs, E, NB);
  k_scanb<<<1, 128, 0, stream>>>(ccur, bbase, rowptr, NB, N, E);
  k_binB<<<NB, B, 0, stream>>>(pairs, ccur, bbase, rowptr, dinv, elist, N);
  // weight prep (both layers, one launch)
  k_prepw2<<<(512 * 128 + 128 * 64 + B - 1) / B, B, 0, stream>>>(
      W1, Wt1h, Wt1l, W2, Wt2h, Wt2l);
  // layer 1: BM=64, BN=128 -> 782 blocks (~3/CU)
  k_gemm_mfma<512, 128, 32, 2, 2><<<(N + 63) / 64, B, 0, stream>>>(
      x, Wt1h, Wt1l, dinv, Hs, N);
  k_gather<128, true><<<(N + 15) / 16, B, 0, stream>>>(rowptr, elist, dinv, Hs, b1, h2, N);
  // layer 2: BM=128, BN=64 -> 391 blocks
  k_gemm_mfma<128, 64, 32, 4, 1><<<(N + 127) / 128, B, 0, stream>>>(
      h2, Wt2h, Wt2l, dinv, Hs2, N);
  k_gather<64, false><<<(N + 31) / 32, B, 0, stream>>>(rowptr, elist, dinv, Hs2, b2, out, N);
}